// Round 1
// baseline (90.536 us; speedup 1.0000x reference)
//
#include <hip/hip_runtime.h>

// ROIAlign: input (B=2, C=256, H=200, W=200) f32, rois (R=512, 5) f32
// output (R, C, 7, 7) f32.  sampling_ratio = 2, spatial_scale = 0.0625.

#define B_  2
#define C_  256
#define H_  200
#define W_  200
#define R_  512
#define PH_ 7
#define PW_ 7

__global__ __launch_bounds__(256) void roialign_kernel(
    const float* __restrict__ input,
    const float* __restrict__ rois,
    float* __restrict__ out,
    int total) {
    int idx = blockIdx.x * blockDim.x + threadIdx.x;
    if (idx >= total) return;

    // idx = ((r*C + c)*PH + ph)*PW + pw
    int pw = idx % PW_;
    int t  = idx / PW_;
    int ph = t % PH_;
    t /= PH_;
    int c = t % C_;
    int r = t / C_;

    const float scale = 0.0625f;
    float bf = rois[r * 5 + 0];
    int   bi = (int)bf;
    float x1 = rois[r * 5 + 1] * scale;
    float y1 = rois[r * 5 + 2] * scale;
    float x2 = rois[r * 5 + 3] * scale;
    float y2 = rois[r * 5 + 4] * scale;

    float roi_w = fmaxf(x2 - x1, 1.0f);
    float roi_h = fmaxf(y2 - y1, 1.0f);
    float bin_w = roi_w * (1.0f / PW_);
    float bin_h = roi_h * (1.0f / PH_);

    const float* in_c = input + ((size_t)bi * C_ + c) * (H_ * W_);

    // Precompute the 2 y-samples and 2 x-samples for this (ph, pw).
    int   ylo_i[2], yhi_i[2];
    float fy[2];
    bool  vy[2];
#pragma unroll
    for (int iy = 0; iy < 2; ++iy) {
        float y = y1 + (float)ph * bin_h + ((float)iy + 0.5f) * bin_h * 0.5f;
        vy[iy] = (y >= -1.0f) && (y <= (float)H_);
        float yc  = fmaxf(y, 0.0f);
        float ylo = floorf(yc);
        bool  at_edge = ylo >= (float)(H_ - 1);
        ylo_i[iy] = (int)fminf(ylo, (float)(H_ - 1));
        yhi_i[iy] = min(ylo_i[iy] + 1, H_ - 1);
        fy[iy] = at_edge ? 0.0f : (yc - ylo);
    }

    int   xlo_i[2], xhi_i[2];
    float fx[2];
    bool  vx[2];
#pragma unroll
    for (int ix = 0; ix < 2; ++ix) {
        float x = x1 + (float)pw * bin_w + ((float)ix + 0.5f) * bin_w * 0.5f;
        vx[ix] = (x >= -1.0f) && (x <= (float)W_);
        float xc  = fmaxf(x, 0.0f);
        float xlo = floorf(xc);
        bool  at_edge = xlo >= (float)(W_ - 1);
        xlo_i[ix] = (int)fminf(xlo, (float)(W_ - 1));
        xhi_i[ix] = min(xlo_i[ix] + 1, W_ - 1);
        fx[ix] = at_edge ? 0.0f : (xc - xlo);
    }

    float acc = 0.0f;
#pragma unroll
    for (int iy = 0; iy < 2; ++iy) {
        const float* row0 = in_c + ylo_i[iy] * W_;
        const float* row1 = in_c + yhi_i[iy] * W_;
        float hy = 1.0f - fy[iy];
#pragma unroll
        for (int ix = 0; ix < 2; ++ix) {
            if (vy[iy] && vx[ix]) {
                float v1 = row0[xlo_i[ix]];
                float v2 = row0[xhi_i[ix]];
                float v3 = row1[xlo_i[ix]];
                float v4 = row1[xhi_i[ix]];
                float hx = 1.0f - fx[ix];
                acc += hy * hx * v1 + hy * fx[ix] * v2 +
                       fy[iy] * hx * v3 + fy[iy] * fx[ix] * v4;
            }
        }
    }
    out[idx] = acc * 0.25f;
}

extern "C" void kernel_launch(void* const* d_in, const int* in_sizes, int n_in,
                              void* d_out, int out_size, void* d_ws, size_t ws_size,
                              hipStream_t stream) {
    const float* input = (const float*)d_in[0];
    const float* rois  = (const float*)d_in[1];
    float* out = (float*)d_out;

    int total = R_ * C_ * PH_ * PW_;  // 6,422,528
    int block = 256;
    int grid  = (total + block - 1) / block;
    roialign_kernel<<<grid, block, 0, stream>>>(input, rois, out, total);
}

// Round 2
// 78.867 us; speedup vs baseline: 1.1480x; 1.1480x over previous
//
#include <hip/hip_runtime.h>

// ROIAlign: input (B=2, C=256, H=200, W=200) f32, rois (R=512, 5) f32
// output (R, C, 7, 7) f32.  sampling_ratio = 2, spatial_scale = 0.0625.
//
// Round 2: latency-bound gather -> 2 channels/thread (c, c+128) to double
// per-wave MLP and amortize geometry; float2 corner loads (xlo, xlo+1 are
// adjacent) to halve VMEM instruction count. Branchless edge handling.

#define B_  2
#define C_  256
#define H_  200
#define W_  200
#define R_  512
#define PH_ 7
#define PW_ 7
#define HW_ (H_ * W_)
#define CH_ (C_ / 2)   // 128: thread handles c0 and c0+128

__global__ __launch_bounds__(256) void roialign_kernel(
    const float* __restrict__ input,
    const float* __restrict__ rois,
    float* __restrict__ out,
    int total) {
    int idx = blockIdx.x * blockDim.x + threadIdx.x;
    if (idx >= total) return;

    // idx = ((r*CH + c0)*PH + ph)*PW + pw
    int pw = idx % PW_;
    int t  = idx / PW_;
    int ph = t % PH_;
    t /= PH_;
    int c0 = t % CH_;
    int r  = t / CH_;

    const float scale = 0.0625f;
    float bf = rois[r * 5 + 0];
    int   bi = (int)bf;
    float x1 = rois[r * 5 + 1] * scale;
    float y1 = rois[r * 5 + 2] * scale;
    float x2 = rois[r * 5 + 3] * scale;
    float y2 = rois[r * 5 + 4] * scale;

    float bin_w = fmaxf(x2 - x1, 1.0f) * (1.0f / PW_);
    float bin_h = fmaxf(y2 - y1, 1.0f) * (1.0f / PH_);

    // y samples: row offsets for lo/hi, frac, valid
    int   ro[2][2];
    float fy[2];
    bool  vy[2];
#pragma unroll
    for (int iy = 0; iy < 2; ++iy) {
        float y = y1 + (float)ph * bin_h + ((float)iy + 0.5f) * bin_h * 0.5f;
        vy[iy] = (y >= -1.0f) && (y <= (float)H_);
        float yc  = fmaxf(y, 0.0f);
        float yl  = floorf(yc);
        bool  edge = yl >= (float)(H_ - 1);
        int   lo = (int)fminf(yl, (float)(H_ - 1));
        int   hi = min(lo + 1, H_ - 1);
        fy[iy] = edge ? 0.0f : (yc - yl);
        ro[iy][0] = lo * W_;
        ro[iy][1] = hi * W_;
    }

    // x samples: float2 base offset + edge-select flag
    int   xo[2];
    bool  sx[2];
    float fx[2];
    bool  vx[2];
#pragma unroll
    for (int ix = 0; ix < 2; ++ix) {
        float x = x1 + (float)pw * bin_w + ((float)ix + 0.5f) * bin_w * 0.5f;
        vx[ix] = (x >= -1.0f) && (x <= (float)W_);
        float xc  = fmaxf(x, 0.0f);
        float xl  = floorf(xc);
        bool  edge = xl >= (float)(W_ - 1);
        int   lo = (int)fminf(xl, (float)(W_ - 1));
        fx[ix] = edge ? 0.0f : (xc - xl);
        sx[ix] = (lo == W_ - 1);
        xo[ix] = min(lo, W_ - 2);   // float2 at xo covers {lo, lo+1} (or {W-2, W-1})
    }

    const float* p0 = input + ((size_t)bi * C_ + c0) * HW_;
    const float* p1 = p0 + (size_t)CH_ * HW_;

    float acc0 = 0.0f, acc1 = 0.0f;
#pragma unroll
    for (int iy = 0; iy < 2; ++iy) {
        float lyw = fy[iy], hyw = 1.0f - lyw;
#pragma unroll
        for (int ix = 0; ix < 2; ++ix) {
            float lxw = fx[ix], hxw = 1.0f - lxw;
            float msk = (vy[iy] && vx[ix]) ? 1.0f : 0.0f;
            float w1 = msk * hyw * hxw;
            float w2 = msk * hyw * lxw;
            float w3 = msk * lyw * hxw;
            float w4 = msk * lyw * lxw;

            float2 a0 = *(const float2*)(p0 + ro[iy][0] + xo[ix]);
            float2 b0 = *(const float2*)(p0 + ro[iy][1] + xo[ix]);
            float2 a1 = *(const float2*)(p1 + ro[iy][0] + xo[ix]);
            float2 b1 = *(const float2*)(p1 + ro[iy][1] + xo[ix]);

            float v1 = sx[ix] ? a0.y : a0.x;
            float v3 = sx[ix] ? b0.y : b0.x;
            acc0 += w1 * v1 + w2 * a0.y + w3 * v3 + w4 * b0.y;

            float u1 = sx[ix] ? a1.y : a1.x;
            float u3 = sx[ix] ? b1.y : b1.x;
            acc1 += w1 * u1 + w2 * a1.y + w3 * u3 + w4 * b1.y;
        }
    }

    int obase = (r * C_ + c0) * (PH_ * PW_) + ph * PW_ + pw;
    out[obase] = acc0 * 0.25f;
    out[obase + CH_ * (PH_ * PW_)] = acc1 * 0.25f;
}

extern "C" void kernel_launch(void* const* d_in, const int* in_sizes, int n_in,
                              void* d_out, int out_size, void* d_ws, size_t ws_size,
                              hipStream_t stream) {
    const float* input = (const float*)d_in[0];
    const float* rois  = (const float*)d_in[1];
    float* out = (float*)d_out;

    int total = R_ * CH_ * PH_ * PW_;  // 3,211,264 threads
    int block = 256;
    int grid  = (total + block - 1) / block;
    roialign_kernel<<<grid, block, 0, stream>>>(input, rois, out, total);
}